// Round 16
// baseline (122.380 us; speedup 1.0000x reference)
//
#include <hip/hip_runtime.h>
#include <hip/hip_bf16.h>

// B=2,S=2048 -> T=4096 tokens; D=1024; N=64 experts; R=64; TOP_K=2.
// Inputs runtime-detected f32 vs bf16 (measured: f32). Outputs f32 flat:
// [0,262144) proj; [262144,270336) idx; [270336,278528) w.
// R25: R24 banked 122.3 (xbf byproduct). Same pattern, last operand:
// neurons f32 (16.8MB cold read + pack VALU in egemm's serial head) ->
// converted during score_part's dispatch by 512 extra blocks (bid>=1024;
// score runs at 3% HBM BW, plenty of spare). Each conv block builds one
// (e,oct) B-slab in LDS with egemm's EXACT staging code (same pack2 RNE ->
// bit-identical) then writes it dense (incl. stride-68 pad) to nbf.
// egemm B-stage becomes a verbatim uint4 copy (8.9MB coalesced, no pack,
// no dtype detect). Everything else byte-identical to the 122.3 build.
// Harness d_ws poison fill (~44us, evicts L3 every iter) untouchable.
// d_ws: f32 w[8192] (32KB); int cnt[64]; int list[64*1024] (256KB);
//       Sb f32[2][4096][64] @+1MB (2MB); P f32[8192][8][64] @+4MB (16MB);
//       xbf u16[4096*1024] @+24MB (8.4MB); nbf u32[512*4352] @+40MB (8.9MB).

typedef unsigned short u16;
typedef unsigned int u32;
typedef __attribute__((ext_vector_type(8))) short short8;
typedef __attribute__((ext_vector_type(4))) float f32x4;

__device__ __forceinline__ float bf2f(u16 u) {
    u32 v = ((u32)u) << 16; float f; __builtin_memcpy(&f, &v, 4); return f;
}
__device__ __forceinline__ u16 f2bf(float f) {  // RNE
    u32 u; __builtin_memcpy(&u, &f, 4);
    u32 r = u + 0x7fff + ((u >> 16) & 1);
    return (u16)(r >> 16);
}
__device__ __forceinline__ u32 pack2(float a, float b) {
    return ((u32)f2bf(b) << 16) | (u32)f2bf(a);
}

#define T_TOKENS 4096
#define DDIM 1024
#define NEXP 64
#define RDIM 64
#define LCAP 1024
#define OUT_IDX_OFF 262144
#define OUT_W_OFF 270336
#define SLAB_U32 4352                 // 64 rows x 68 u32 (stride-68 image)

struct LdBF {
    const u16* p;
    __device__ __forceinline__ float4 ld4(size_t i) const {
        ushort4 v = *(const ushort4*)(p + i);
        return make_float4(bf2f(v.x), bf2f(v.y), bf2f(v.z), bf2f(v.w));
    }
    __device__ __forceinline__ float ld1(size_t i) const { return bf2f(p[i]); }
};
struct LdF32 {
    const float* p;
    __device__ __forceinline__ float4 ld4(size_t i) const { return *(const float4*)(p + i); }
    __device__ __forceinline__ float ld1(size_t i) const { return p[i]; }
};

// in-block dtype probe: 1 if f32, 0 if bf16 (all blocks same verdict).
__device__ __forceinline__ int detect_f32(const u16* x, int* lds_cnt) {
    if (threadIdx.x == 0) *lds_cnt = 0;
    __syncthreads();
    if (threadIdx.x < 256) {
        unsigned e = (x[threadIdx.x] >> 7) & 0xFF;
        if (e >= 0x68 && e <= 0x88) atomicAdd(lds_cnt, 1);
    }
    __syncthreads();
    int f = (*lds_cnt < 200) ? 1 : 0;
    __syncthreads();
    return f;
}

// ---------------- neurons -> bf16 slab conversion (runs inside kernel A) --
// One block per (e,oct): build the Bb image in LDS with egemm's staging
// code (same pack2 RNE -> bit-identical), then dense coalesced copy to nbf.
template <class LD>
__device__ __forceinline__ void conv_body(LD nld, int cb, u32* bb /*LDS 4352*/,
                                          u32* nbf) {
    const int tid = threadIdx.x;
    const int e = cb >> 3;
    const int oct = cb & 7;
    const size_t nbase = (size_t)e * (DDIM * RDIM);
    const int k0 = oct * 128;
    const int rq = tid & 15;
    const int kpB = tid >> 4;
#pragma unroll
    for (int h = 0; h < 4; ++h) {
        int kp = kpB + h * 16;
        float4 g0 = nld.ld4(nbase + (size_t)(k0 + 2 * kp) * RDIM + rq * 4);
        float4 g1 = nld.ld4(nbase + (size_t)(k0 + 2 * kp + 1) * RDIM + rq * 4);
        bb[(rq * 4 + 0) * 68 + kp] = pack2(g0.x, g1.x);
        bb[(rq * 4 + 1) * 68 + kp] = pack2(g0.y, g1.y);
        bb[(rq * 4 + 2) * 68 + kp] = pack2(g0.z, g1.z);
        bb[(rq * 4 + 3) * 68 + kp] = pack2(g0.w, g1.w);
    }
    __syncthreads();
    u32* dst = nbf + (size_t)cb * SLAB_U32;
    for (int i = tid; i < SLAB_U32; i += 256) dst[i] = bb[i];
}

// ---------------- Kernel A: score GEMM partials (K-split) + conversions ---
// 1536 blocks x 256 thr. bid<1024: score (g=bid>>1 tokens [8g,8g+8),
// kh=bid&1 K-half; 8 chunks of 64 rotated by bid&7; R14-proven M4xE8 core,
// 60 VGPR; partials -> Sb; bf16(x) byproduct -> xbf). bid>=1024: neurons
// slab conversion (cb=bid-1024) absorbed by score's idle BW/CUs.
// Block 0 zeroes wsCnt (replaces the hipMemsetAsync dispatch).
template <class LD>
__device__ __forceinline__ void score_body(LD xld, LD rwld,
                                           float* xs /*8*68*/, float* wt /*64*68*/,
                                           float* sc /*8*65*/, float* Sb, u16* xbf) {
    const int tid = threadIdx.x;
    const int g = blockIdx.x >> 1;
    const int kh = blockIdx.x & 1;
    const size_t t0 = (size_t)g * 8;
    const int kbase = kh * 512;
    const int wv = tid >> 6;
    const int lane = tid & 63;
    const int tg = lane & 1;
    const int eg = (lane >> 1) & 7;
    const int kql = (lane >> 4) & 3;
    const int dd = 4 * kql + 16 * wv;
    const int kc0 = blockIdx.x & 7;    // rotated chunk start (8 chunks)

    const int sm = tid >> 4;            // staging roles (coalesced)
    const int sd4 = (tid & 15) * 4;

    float acc[4][8];
#pragma unroll
    for (int mi = 0; mi < 4; ++mi)
#pragma unroll
        for (int ei = 0; ei < 8; ++ei) acc[mi][ei] = 0.f;

    float4 px;
    if (tid < 128) px = xld.ld4((t0 + sm) * DDIM + kbase + kc0 * 64 + sd4);
    float4 pw[4];
#pragma unroll
    for (int h = 0; h < 4; ++h) {
        int i4 = tid + h * 256;
        pw[h] = rwld.ld4((size_t)(i4 >> 4) * DDIM + kbase + kc0 * 64 + (i4 & 15) * 4);
    }

    for (int i = 0; i < 8; ++i) {
        if (i > 0) __syncthreads();
        if (tid < 128) {
            *(float4*)&xs[sm * 68 + sd4] = px;
            // bf16 byproduct: 4 floats -> 2 packed u32 (8B store, coalesced)
            int kchn = kbase + ((i + kc0) & 7) * 64;
            uint2 b;
            b.x = pack2(px.x, px.y);
            b.y = pack2(px.z, px.w);
            *(uint2*)&xbf[(t0 + sm) * DDIM + kchn + sd4] = b;
        }
#pragma unroll
        for (int h = 0; h < 4; ++h) {
            int i4 = tid + h * 256;
            *(float4*)&wt[(i4 >> 4) * 68 + (i4 & 15) * 4] = pw[h];
        }
        __syncthreads();

        if (i < 7) {
            int kn = kbase + ((i + 1 + kc0) & 7) * 64;
            if (tid < 128) px = xld.ld4((t0 + sm) * DDIM + kn + sd4);
#pragma unroll
            for (int h = 0; h < 4; ++h) {
                int i4 = tid + h * 256;
                pw[h] = rwld.ld4((size_t)(i4 >> 4) * DDIM + kn + (i4 & 15) * 4);
            }
        }

        float4 xv[4], wv4[8];
#pragma unroll
        for (int mi = 0; mi < 4; ++mi)
            xv[mi] = *(const float4*)&xs[(tg + 2 * mi) * 68 + dd];
#pragma unroll
        for (int ei = 0; ei < 8; ++ei)
            wv4[ei] = *(const float4*)&wt[(eg + 8 * ei) * 68 + dd];
#pragma unroll
        for (int mi = 0; mi < 4; ++mi)
#pragma unroll
            for (int ei = 0; ei < 8; ++ei)
                acc[mi][ei] += xv[mi].x * wv4[ei].x + xv[mi].y * wv4[ei].y +
                               xv[mi].z * wv4[ei].z + xv[mi].w * wv4[ei].w;
    }

    // in-wave k-quad reduce (deterministic tree over kql)
#pragma unroll
    for (int mi = 0; mi < 4; ++mi)
#pragma unroll
        for (int ei = 0; ei < 8; ++ei) {
            float v = acc[mi][ei];
            v += __shfl_xor(v, 16, 64);
            v += __shfl_xor(v, 32, 64);
            acc[mi][ei] = v;
        }
    __syncthreads();

    // cross-wave reduce: sequential wave phases (deterministic order)
    for (int w = 0; w < 4; ++w) {
        if (wv == w && kql == 0) {
#pragma unroll
            for (int mi = 0; mi < 4; ++mi)
#pragma unroll
                for (int ei = 0; ei < 8; ++ei) {
                    int idx = (tg + 2 * mi) * 65 + eg + 8 * ei;
                    sc[idx] = (w == 0) ? acc[mi][ei] : sc[idx] + acc[mi][ei];
                }
        }
        __syncthreads();
    }

    // store this K-half's partial scores: 8 tokens x 64 experts
    if (tid < 128) {
        int t = tid >> 4, e4 = (tid & 15) * 4;
        const float* s = &sc[t * 65 + e4];
        float4 v = make_float4(s[0], s[1], s[2], s[3]);
        *(float4*)&Sb[((size_t)kh * T_TOKENS + t0 + t) * 64 + e4] = v;
    }
}

__global__ __launch_bounds__(256, 4) void score_part(const void* x, const void* rw,
                                                     const void* neurons,
                                                     float* Sb, int* wsCnt, u16* xbf,
                                                     u32* nbf) {
    __shared__ float xs[8 * 68];
    __shared__ __align__(16) float wt[64 * 68];   // doubles as conv slab buffer
    __shared__ float sc[8 * 65];
    __shared__ int dc;
    if (blockIdx.x == 0 && threadIdx.x < NEXP) wsCnt[threadIdx.x] = 0;
    int f = detect_f32((const u16*)x, &dc);
    if (blockIdx.x >= 1024) {
        int cb = blockIdx.x - 1024;
        if (f)
            conv_body(LdF32{(const float*)neurons}, cb, (u32*)wt, nbf);
        else
            conv_body(LdBF{(const u16*)neurons}, cb, (u32*)wt, nbf);
        return;
    }
    if (f)
        score_body(LdF32{(const float*)x}, LdF32{(const float*)rw}, xs, wt, sc, Sb, xbf);
    else
        score_body(LdBF{(const u16*)x}, LdBF{(const u16*)rw}, xs, wt, sc, Sb, xbf);
}

// ---------------- Kernel A2: top-2 + softmax + outputs + expert lists -----
// 64 blocks x 64 thr; 1 token/thread. score[t][e] = Sb[0][t][e]+Sb[1][t][e]
// (2-addend fl-sum: order-independent => deterministic). Same scan/tie-break
// semantics as reference (strict >, ascending j).
__global__ __launch_bounds__(64) void topk_softmax(const float* Sb, float* out,
                                                   float* wsW, int* wsCnt,
                                                   int* wsList) {
    int t = blockIdx.x * 64 + threadIdx.x;       // [0, 4096)
    const float* s0 = Sb + (size_t)t * 64;
    const float* s1 = Sb + ((size_t)T_TOKENS + t) * 64;
    float best = -1e30f, secv = -1e30f;
    int bi = 0, si = 0;
    for (int j = 0; j < NEXP; j += 4) {
        float4 a = *(const float4*)(s0 + j);
        float4 b = *(const float4*)(s1 + j);
        float v0 = a.x + b.x, v1 = a.y + b.y, v2 = a.z + b.z, v3 = a.w + b.w;
        if (v0 > best) { secv = best; si = bi; best = v0; bi = j; }
        else if (v0 > secv) { secv = v0; si = j; }
        if (v1 > best) { secv = best; si = bi; best = v1; bi = j + 1; }
        else if (v1 > secv) { secv = v1; si = j + 1; }
        if (v2 > best) { secv = best; si = bi; best = v2; bi = j + 2; }
        else if (v2 > secv) { secv = v2; si = j + 2; }
        if (v3 > best) { secv = best; si = bi; best = v3; bi = j + 3; }
        else if (v3 > secv) { secv = v3; si = j + 3; }
    }
    float w0 = 1.0f / (1.0f + expf(secv - best));
    float w1 = 1.0f - w0;
    out[OUT_IDX_OFF + (size_t)t * 2 + 0] = (float)bi;
    out[OUT_IDX_OFF + (size_t)t * 2 + 1] = (float)si;
    out[OUT_W_OFF + (size_t)t * 2 + 0] = w0;
    out[OUT_W_OFF + (size_t)t * 2 + 1] = w1;
    wsW[t * 2 + 0] = w0;
    wsW[t * 2 + 1] = w1;
    int p0 = atomicAdd(&wsCnt[bi], 1);
    if (p0 < LCAP) wsList[bi * LCAP + p0] = t * 2 + 0;
    int p1 = atomicAdd(&wsCnt[si], 1);
    if (p1 < LCAP) wsList[si * LCAP + p1] = t * 2 + 1;
}

// ---------------- Kernel B: per-expert bf16 MFMA GEMM, K-eighth persist-B --
// 512 blocks: e = bid>>3, oct = bid&7; k window [oct*128, oct*128+128).
// B-stage is now a verbatim uint4 copy of the pre-converted nbf slab
// (bit-identical to the old in-kernel pack). A from xbf (bf16 byproduct).
// No dtype detect needed (both operands pre-converted). Tile loop:
// 2-deep A-prefetch (named reg sets + swap), 4 MFMA, plain stores of raw
// partials to P[t2*512 + oct*64 + col]. No atomics.
__global__ __launch_bounds__(256, 2) void expert_gemm(const u16* xbf, const u32* nbf,
                                                      const int* wsCnt, const int* wsList,
                                                      float* P) {
    __shared__ __align__(16) u16 Ab[16 * 136];
    __shared__ __align__(16) u16 Bb[64 * 136];
    __shared__ int eL[LCAP];
    const int tid = threadIdx.x;
    const int e = blockIdx.x >> 3;
    const int oct = blockIdx.x & 7;
    const int cntE = min(wsCnt[e], LCAP);
    if (cntE <= 0) return;                       // uniform exit
    const int wv = tid >> 6;
    const int lane = tid & 63;
    const int l15 = lane & 15, quad = lane >> 4;
    const int k0 = oct * 128;

    for (int j = tid; j < cntE; j += 256) eL[j] = wsList[e * LCAP + j];

    // B-stage: verbatim slab copy (1088 uint4; threads 0-63 do 5, rest 4)
    {
        const uint4* src = (const uint4*)(nbf + (size_t)blockIdx.x * SLAB_U32);
        uint4* dst = (uint4*)Bb;
        for (int i = tid; i < SLAB_U32 / 4; i += 256) dst[i] = src[i];
    }
    __syncthreads();                              // Bb + eL visible

    const int rowA = tid >> 4;
    const int kqA = tid & 15;
    const int ntiles = (cntE + 15) >> 4;

    // 2-deep A prefetch from xbf: one uint4 (8 bf16) per thread per tile.
    uint4 ca, na;
    {
        int t2r = eL[min(rowA, cntE - 1)];
        ca = *(const uint4*)&xbf[(size_t)(t2r >> 1) * DDIM + k0 + kqA * 8];
    }
    na = ca;
    if (ntiles > 1) {
        int t2r = eL[min(16 + rowA, cntE - 1)];
        na = *(const uint4*)&xbf[(size_t)(t2r >> 1) * DDIM + k0 + kqA * 8];
    }

    for (int ti = 0; ti < ntiles; ++ti) {
        const int base = ti * 16;
        const int valid = min(16, cntE - base);
        if (ti > 0) __syncthreads();
        *(uint4*)&((u32*)Ab)[rowA * 68 + kqA * 4] = ca;
        __syncthreads();
        if (ti + 2 < ntiles) {
            int t2r = eL[min(base + 32 + rowA, cntE - 1)];
            ca = *(const uint4*)&xbf[(size_t)(t2r >> 1) * DDIM + k0 + kqA * 8];
        }

        f32x4 acc = {0.f, 0.f, 0.f, 0.f};
#pragma unroll
        for (int ko = 0; ko < 4; ++ko) {
            int kofs = ko * 32 + quad * 8;
            short8 bfr = *(const short8*)&Bb[(16 * wv + l15) * 136 + kofs];
            short8 af = *(const short8*)&Ab[l15 * 136 + kofs];
            acc = __builtin_amdgcn_mfma_f32_16x16x32_bf16(af, bfr, acc, 0, 0, 0);
        }

#pragma unroll
        for (int reg = 0; reg < 4; ++reg) {
            int m = quad * 4 + reg;
            if (m < valid) {
                int t2 = eL[base + m];
                P[(size_t)t2 * 512 + oct * 64 + 16 * wv + l15] = acc[reg];
            }
        }

        uint4 s = ca;
        ca = na;
        na = s;
    }
}

// ---------------- Kernel C: combine partials -------------------------------
// out[t][r] = sum_s wsW[2t+s] * sum_oct P[(2t+s)*512 + oct*64 + r].
// 1024 blocks x 256 thr; 1 element/thread; fully coalesced 256B segments.
__global__ __launch_bounds__(256) void combine(const float* P, const float* wsW,
                                               float* out) {
    int i = blockIdx.x * 256 + threadIdx.x;      // [0, 262144)
    int t = i >> 6, r = i & 63;
    const float* p0 = P + (size_t)(2 * t) * 512 + r;
    const float* p1 = P + (size_t)(2 * t + 1) * 512 + r;
    float s0 = 0.f, s1 = 0.f;
#pragma unroll
    for (int o = 0; o < 8; ++o) {
        s0 += p0[o * 64];
        s1 += p1[o * 64];
    }
    out[i] = wsW[2 * t] * s0 + wsW[2 * t + 1] * s1;
}

extern "C" void kernel_launch(void* const* d_in, const int* in_sizes, int n_in,
                              void* d_out, int out_size, void* d_ws, size_t ws_size,
                              hipStream_t stream) {
    const void* x = d_in[0];
    const void* rw = d_in[1];
    const void* neurons = d_in[2];
    float* out = (float*)d_out;

    char* wsc = (char*)d_ws;
    float* wsW = (float*)wsc;                                  // 32 KB
    int* wsCnt = (int*)(wsc + 32 * 1024);                      // 256 B
    int* wsList = (int*)(wsc + 32 * 1024 + 256);               // 256 KB
    float* Sb = (float*)(wsc + (1 << 20));                     // 2 MB @ +1MB
    float* P = (float*)(wsc + (4 << 20));                      // 16 MB @ +4MB
    u16* xbf = (u16*)(wsc + (24 << 20));                       // 8.4 MB @ +24MB
    u32* nbf = (u32*)(wsc + (40 << 20));                       // 8.9 MB @ +40MB

    score_part<<<1536, 256, 0, stream>>>(x, rw, neurons, Sb, wsCnt, xbf, nbf);
    topk_softmax<<<64, 64, 0, stream>>>(Sb, out, wsW, wsCnt, wsList);
    expert_gemm<<<512, 256, 0, stream>>>(xbf, nbf, wsCnt, wsList, P);
    combine<<<1024, 256, 0, stream>>>(P, wsW, out);
}